// Round 12
// baseline (824.629 us; speedup 1.0000x reference)
//
#include <hip/hip_runtime.h>
#include <cstdint>
#include <cstddef>

#define IN_F  4096
#define OUT_F 16384
#define NROWS 8192   // 2*4096 tokens
#define NKT   64     // K-tiles of 64 bytes

typedef __attribute__((ext_vector_type(4)))  int int32x4;
typedef __attribute__((ext_vector_type(16))) int int32x16;

// async global->LDS, 16B/lane (dest = wave-uniform base, HW adds lane*16)
__device__ __forceinline__ void gload_lds16(const void* g, void* s) {
    __builtin_amdgcn_global_load_lds((const __attribute__((address_space(1))) void*)g,
                                     (__attribute__((address_space(3))) void*)s,
                                     16, 0, 0);
}

// ---------------------------------------------------------------------------
// Layouts (fragment-major, shared by producers and GEMM staging):
//   xqS: [mtile 32][kt 64][c 4][row 256][16B]   c = ksub*2+kh
//   wtS: [ntile 64][kt 64][c 4][col 256][16B]
// ---------------------------------------------------------------------------

// Kernel 1: weight [K=4096][N=16384] int32 -> wtS (narrow + transpose + tile)
__global__ __launch_bounds__(256) void transpose_kernel(const int* __restrict__ w,
                                                        uint8_t* __restrict__ wtS) {
    __shared__ uint8_t tile[64][68];
    const int t  = threadIdx.x;
    const int nb = blockIdx.x * 64;
    const int kt = blockIdx.y;          // K-tile = 64 k-rows
    const int kb = kt * 64;

#pragma unroll
    for (int p = 0; p < 4; ++p) {
        const int r = p * 16 + (t >> 4);
        const int c4 = t & 15;
        int4 u = *reinterpret_cast<const int4*>(w + (size_t)(kb + r) * OUT_F + nb + c4 * 4);
        uint32_t packed = (uint32_t)(u.x & 255) | ((uint32_t)(u.y & 255) << 8)
                        | ((uint32_t)(u.z & 255) << 16) | ((uint32_t)(u.w & 255) << 24);
        *reinterpret_cast<uint32_t*>(&tile[r][c4 * 4]) = packed;
    }
    __syncthreads();

    const int col = t >> 2;             // 0..63
    const int c   = t & 3;              // ksub*2+kh
    uint4 o;
    uint32_t* op = reinterpret_cast<uint32_t*>(&o);
#pragma unroll
    for (int j = 0; j < 4; ++j) {
        const int kk = c * 16 + j * 4;
        op[j] = (uint32_t)tile[kk][col] | ((uint32_t)tile[kk + 1][col] << 8)
              | ((uint32_t)tile[kk + 2][col] << 16) | ((uint32_t)tile[kk + 3][col] << 24);
    }
    const int ntile = nb >> 8;
    const int colg  = (nb & 255) + col;
    *reinterpret_cast<uint4*>(wtS + (((size_t)ntile * NKT + kt) * 4 + c) * 4096 + colg * 16) = o;
}

// Kernel 2: per-row dynamic quant -> xqS (fragment-major) + xs
__global__ __launch_bounds__(256) void quant_kernel(const float* __restrict__ x,
                                                    uint8_t* __restrict__ xqS,
                                                    float* __restrict__ xs) {
    const int t = threadIdx.x;
    const int w = t >> 6, l = t & 63;
    const int half = l >> 5, lh = l & 31;
    const int m = blockIdx.x * 8 + w * 2 + half;
    const float* xr = x + (size_t)m * IN_F;

    float am = 0.0f;
#pragma unroll 8
    for (int jj = 0; jj < 32; ++jj) {
        float4 v = reinterpret_cast<const float4*>(xr)[jj * 32 + lh];
        am = fmaxf(am, fmaxf(fmaxf(fabsf(v.x), fabsf(v.y)),
                             fmaxf(fabsf(v.z), fabsf(v.w))));
    }
#pragma unroll
    for (int off = 16; off; off >>= 1) am = fmaxf(am, __shfl_xor(am, off));

    const float scale = fmaxf(am / 127.0f, 1e-12f);
    if (lh == 0) xs[m] = scale;

    const int mtile = m >> 8, mrow = m & 255;
    uint8_t* ob = xqS + (size_t)mtile * (NKT * 16384) + (size_t)mrow * 16;
#pragma unroll
    for (int j = 0; j < 8; ++j) {
        const int k0 = lh * 128 + j * 16;
        const float4* vp = reinterpret_cast<const float4*>(xr + k0);
        uint4 pk;
        uint32_t* pp = reinterpret_cast<uint32_t*>(&pk);
#pragma unroll
        for (int q = 0; q < 4; ++q) {
            float4 v = vp[q];
            float r0 = fminf(127.f, fmaxf(-128.f, rintf(v.x / scale)));
            float r1 = fminf(127.f, fmaxf(-128.f, rintf(v.y / scale)));
            float r2 = fminf(127.f, fmaxf(-128.f, rintf(v.z / scale)));
            float r3 = fminf(127.f, fmaxf(-128.f, rintf(v.w / scale)));
            pp[q] = ((uint32_t)((int)r0 & 255)) | ((uint32_t)((int)r1 & 255) << 8)
                  | ((uint32_t)((int)r2 & 255) << 16) | ((uint32_t)((int)r3 & 255) << 24);
        }
        const int ktk = k0 >> 6;
        const int c   = (k0 >> 4) & 3;
        *reinterpret_cast<uint4*>(ob + ((size_t)ktk * 4 + c) * 4096) = pk;
    }
}

// ---------------------------------------------------------------------------
// Kernel 3: int8 GEMM, **256x128 tile, 4 waves (2Mx2N, 128x64/wave,
// acc[4][2]), double-buffered 48KB LDS -> 2 blocks/CU** (8 waves/CU at
// ~220 unified regs/wave — fits the 512-reg/SIMD pool at 2 waves/SIMD).
// Round-5/8 reg-dbuf schedule; depth-1 staging (L2-hot sources) with
// vmcnt(0) at the tile boundary; co-resident block hides the drain,
// the barriers, and the 128KB C-write epilogue.
// ---------------------------------------------------------------------------
__global__ __launch_bounds__(256, 2) void gemm_kernel(const uint8_t* __restrict__ xqS,
                                                      const uint8_t* __restrict__ wtS,
                                                      const float* __restrict__ xs,
                                                      const float* __restrict__ wsc,
                                                      const float* __restrict__ bias,
                                                      float* __restrict__ out) {
    __shared__ uint8_t ldsA[2][16384];   // A tile: [c 4][row 256][16B]
    __shared__ uint8_t ldsB[2][8192];    // B tile: [c 4][col 128][16B]

    const int t    = threadIdx.x;
    const int lane = t & 63;
    const int wid  = t >> 6;                   // 0..3
    const int wm   = wid >> 1, wn = wid & 1;   // wave tile: 128 rows x 64 cols

    // XCD mapping: 4096 blocks; xcd owns mt 4x..4x+3; mt-inner / nt-outer so
    // concurrent neighbors (incl. the CU-coresident block) share a B panel.
    const int xcd = blockIdx.x & 7;
    const int i   = blockIdx.x >> 3;           // 0..511 local on this XCD
    const int mt  = xcd * 4 + (i & 3);         // 0..31  (256-row A panel)
    const int nt2 = i >> 2;                    // 0..127 (128-col B panel)

    const uint8_t* aBase = xqS + (size_t)mt * (NKT * 16384);
    const uint8_t* bBase = wtS + (size_t)(nt2 >> 1) * (NKT * 16384) + (nt2 & 1) * 2048;
    const int t16  = t * 16;
    const int wofs = wid * 1024;
    const int bOff = (t >> 7) * 4096 + (t & 127) * 16;   // B stage per-lane src

    // fragment read bases (lane-contiguous 16B: conflict-free)
    const int aRd0 = (lane >> 5) * 4096 + wm * 2048 + (lane & 31) * 16;  // +8192 for s=1
    const int bRd0 = (lane >> 5) * 2048 + wn * 1024 + (lane & 31) * 16;  // +4096 for s=1

    int32x16 acc[4][2] = {};
    int32x4 af0[4], af1[4], bf0[2], bf1[2];

    // prologue: stage tile 0 into buf 0
#pragma unroll
    for (int g = 0; g < 4; ++g)
        gload_lds16(aBase + g * 4096 + t16, &ldsA[0][0] + g * 4096 + wofs);
#pragma unroll
    for (int g = 0; g < 2; ++g)
        gload_lds16(bBase + g * 8192 + bOff, &ldsB[0][0] + g * 4096 + wofs);
    asm volatile("s_waitcnt vmcnt(0)" ::: "memory");
    __builtin_amdgcn_s_barrier();
    __builtin_amdgcn_sched_barrier(0);

    // fragments (tile 0, s=0) -> f0
#pragma unroll
    for (int mr = 0; mr < 4; ++mr)
        af0[mr] = *reinterpret_cast<const int32x4*>(&ldsA[0][0] + aRd0 + mr * 512);
#pragma unroll
    for (int nr = 0; nr < 2; ++nr)
        bf0[nr] = *reinterpret_cast<const int32x4*>(&ldsB[0][0] + bRd0 + nr * 512);

    for (int kt = 0; kt < NKT; ++kt) {
        const uint8_t* bufA  = &ldsA[kt & 1][0];
        const uint8_t* bufB  = &ldsB[kt & 1][0];
        uint8_t*       nbufA = &ldsA[(kt + 1) & 1][0];
        uint8_t*       nbufB = &ldsB[(kt + 1) & 1][0];

        // 1. stage tile kt+1 (WAR: its readers drained before last barrier)
        if (kt < NKT - 1) {
            const size_t srcn = (size_t)(kt + 1) * 16384;
#pragma unroll
            for (int g = 0; g < 4; ++g)
                gload_lds16(aBase + srcn + g * 4096 + t16, nbufA + g * 4096 + wofs);
#pragma unroll
            for (int g = 0; g < 2; ++g)
                gload_lds16(bBase + srcn + g * 8192 + bOff, nbufB + g * 4096 + wofs);
        }

        // 2. ds_reads (kt, s=1) -> f1 (overlap with MFMA f0 below)
#pragma unroll
        for (int mr = 0; mr < 4; ++mr)
            af1[mr] = *reinterpret_cast<const int32x4*>(bufA + 8192 + aRd0 + mr * 512);
#pragma unroll
        for (int nr = 0; nr < 2; ++nr)
            bf1[nr] = *reinterpret_cast<const int32x4*>(bufB + 4096 + bRd0 + nr * 512);

        // 3. MFMA cluster on f0 (LDS pipe serves f1's reads underneath)
        __builtin_amdgcn_s_setprio(1);
#pragma unroll
        for (int mr = 0; mr < 4; ++mr)
#pragma unroll
            for (int nr = 0; nr < 2; ++nr)
                acc[mr][nr] = __builtin_amdgcn_mfma_i32_32x32x32_i8(af0[mr], bf0[nr], acc[mr][nr], 0, 0, 0);
        __builtin_amdgcn_s_setprio(0);

        if (kt < NKT - 1) {
            // 4. drain my ds_reads (WAR for next stage) + staged tile landed
            asm volatile("s_waitcnt lgkmcnt(0)" ::: "memory");
            asm volatile("s_waitcnt vmcnt(0)" ::: "memory");
            __builtin_amdgcn_s_barrier();
            __builtin_amdgcn_sched_barrier(0);

            // 5. ds_reads (kt+1, s=0) -> f0 (overlap with MFMA f1 below)
#pragma unroll
            for (int mr = 0; mr < 4; ++mr)
                af0[mr] = *reinterpret_cast<const int32x4*>(nbufA + aRd0 + mr * 512);
#pragma unroll
            for (int nr = 0; nr < 2; ++nr)
                bf0[nr] = *reinterpret_cast<const int32x4*>(nbufB + bRd0 + nr * 512);
        }

        // 6. MFMA cluster on f1
        __builtin_amdgcn_s_setprio(1);
#pragma unroll
        for (int mr = 0; mr < 4; ++mr)
#pragma unroll
            for (int nr = 0; nr < 2; ++nr)
                acc[mr][nr] = __builtin_amdgcn_mfma_i32_32x32x32_i8(af1[mr], bf1[nr], acc[mr][nr], 0, 0, 0);
        __builtin_amdgcn_s_setprio(0);
    }

    // epilogue: C/D 32x32 layout: col = lane&31, row = (g&3)+8*(g>>2)+4*(lane>>5)
    const int row0 = mt * 256 + wm * 128;
    const int col0 = nt2 * 128 + wn * 64;
#pragma unroll
    for (int mr = 0; mr < 4; ++mr) {
        const int rbase = row0 + mr * 32 + 4 * (lane >> 5);
        float xsv[16];
#pragma unroll
        for (int g = 0; g < 16; ++g)
            xsv[g] = xs[rbase + (g & 3) + 8 * (g >> 2)];
#pragma unroll
        for (int nr = 0; nr < 2; ++nr) {
            const int n = col0 + nr * 32 + (lane & 31);
            const float ws_n = wsc[n];
            const float b_n  = bias[n];
#pragma unroll
            for (int g = 0; g < 16; ++g) {
                const int m = rbase + (g & 3) + 8 * (g >> 2);
                out[(size_t)m * OUT_F + n] = (float)acc[mr][nr][g] * xsv[g] * ws_n + b_n;
            }
        }
    }
}

// ---------------------------------------------------------------------------
extern "C" void kernel_launch(void* const* d_in, const int* in_sizes, int n_in,
                              void* d_out, int out_size, void* d_ws, size_t ws_size,
                              hipStream_t stream) {
    const float* x    = (const float*)d_in[0];
    const int*   wq   = (const int*)d_in[1];     // int8 pushed as int32 [4096][16384]
    const float* wsc  = (const float*)d_in[2];
    const float* bias = (const float*)d_in[3];
    float* out = (float*)d_out;

    uint8_t* ws  = (uint8_t*)d_ws;
    uint8_t* wtS = ws;                                               // 64 MiB
    uint8_t* xqS = ws + (size_t)IN_F * OUT_F;                        // 32 MiB
    float*   xs  = (float*)(ws + (size_t)IN_F * OUT_F + (size_t)NROWS * IN_F);

    transpose_kernel<<<dim3(OUT_F / 64, IN_F / 64), 256, 0, stream>>>(wq, wtS);
    quant_kernel<<<NROWS / 8, 256, 0, stream>>>(x, xqS, xs);
    gemm_kernel<<<(NROWS / 256) * (OUT_F / 128), 256, 0, stream>>>(xqS, wtS, xs, wsc, bias, out);
}

// Round 13
// 770.710 us; speedup vs baseline: 1.0700x; 1.0700x over previous
//
#include <hip/hip_runtime.h>
#include <cstdint>
#include <cstddef>

#define IN_F  4096
#define OUT_F 16384
#define NROWS 8192   // 2*4096 tokens
#define NKT   64     // K-tiles of 64 bytes

typedef __attribute__((ext_vector_type(4)))  int int32x4;
typedef __attribute__((ext_vector_type(16))) int int32x16;

// async global->LDS, 16B/lane (dest = wave-uniform base, HW adds lane*16)
__device__ __forceinline__ void gload_lds16(const void* g, void* s) {
    __builtin_amdgcn_global_load_lds((const __attribute__((address_space(1))) void*)g,
                                     (__attribute__((address_space(3))) void*)s,
                                     16, 0, 0);
}

// ---------------------------------------------------------------------------
// Layouts (fragment-major, shared by producers and GEMM staging):
//   xqS: [mtile 32][kt 64][c 4][row 256][16B]   c = ksub*2+kh
//   wtS: [ntile 64][kt 64][c 4][col 256][16B]
// ---------------------------------------------------------------------------

// Kernel 1: weight [K=4096][N=16384] int32 -> wtS (narrow + transpose + tile)
__global__ __launch_bounds__(256) void transpose_kernel(const int* __restrict__ w,
                                                        uint8_t* __restrict__ wtS) {
    __shared__ uint8_t tile[64][68];
    const int t  = threadIdx.x;
    const int nb = blockIdx.x * 64;
    const int kt = blockIdx.y;          // K-tile = 64 k-rows
    const int kb = kt * 64;

#pragma unroll
    for (int p = 0; p < 4; ++p) {
        const int r = p * 16 + (t >> 4);
        const int c4 = t & 15;
        int4 u = *reinterpret_cast<const int4*>(w + (size_t)(kb + r) * OUT_F + nb + c4 * 4);
        uint32_t packed = (uint32_t)(u.x & 255) | ((uint32_t)(u.y & 255) << 8)
                        | ((uint32_t)(u.z & 255) << 16) | ((uint32_t)(u.w & 255) << 24);
        *reinterpret_cast<uint32_t*>(&tile[r][c4 * 4]) = packed;
    }
    __syncthreads();

    const int col = t >> 2;             // 0..63
    const int c   = t & 3;              // ksub*2+kh
    uint4 o;
    uint32_t* op = reinterpret_cast<uint32_t*>(&o);
#pragma unroll
    for (int j = 0; j < 4; ++j) {
        const int kk = c * 16 + j * 4;
        op[j] = (uint32_t)tile[kk][col] | ((uint32_t)tile[kk + 1][col] << 8)
              | ((uint32_t)tile[kk + 2][col] << 16) | ((uint32_t)tile[kk + 3][col] << 24);
    }
    const int ntile = nb >> 8;
    const int colg  = (nb & 255) + col;
    *reinterpret_cast<uint4*>(wtS + (((size_t)ntile * NKT + kt) * 4 + c) * 4096 + colg * 16) = o;
}

// Kernel 2: per-row dynamic quant -> xqS (fragment-major) + xs
__global__ __launch_bounds__(256) void quant_kernel(const float* __restrict__ x,
                                                    uint8_t* __restrict__ xqS,
                                                    float* __restrict__ xs) {
    const int t = threadIdx.x;
    const int w = t >> 6, l = t & 63;
    const int half = l >> 5, lh = l & 31;
    const int m = blockIdx.x * 8 + w * 2 + half;
    const float* xr = x + (size_t)m * IN_F;

    float am = 0.0f;
#pragma unroll 8
    for (int jj = 0; jj < 32; ++jj) {
        float4 v = reinterpret_cast<const float4*>(xr)[jj * 32 + lh];
        am = fmaxf(am, fmaxf(fmaxf(fabsf(v.x), fabsf(v.y)),
                             fmaxf(fabsf(v.z), fabsf(v.w))));
    }
#pragma unroll
    for (int off = 16; off; off >>= 1) am = fmaxf(am, __shfl_xor(am, off));

    const float scale = fmaxf(am / 127.0f, 1e-12f);
    if (lh == 0) xs[m] = scale;

    const int mtile = m >> 8, mrow = m & 255;
    uint8_t* ob = xqS + (size_t)mtile * (NKT * 16384) + (size_t)mrow * 16;
#pragma unroll
    for (int j = 0; j < 8; ++j) {
        const int k0 = lh * 128 + j * 16;
        const float4* vp = reinterpret_cast<const float4*>(xr + k0);
        uint4 pk;
        uint32_t* pp = reinterpret_cast<uint32_t*>(&pk);
#pragma unroll
        for (int q = 0; q < 4; ++q) {
            float4 v = vp[q];
            float r0 = fminf(127.f, fmaxf(-128.f, rintf(v.x / scale)));
            float r1 = fminf(127.f, fmaxf(-128.f, rintf(v.y / scale)));
            float r2 = fminf(127.f, fmaxf(-128.f, rintf(v.z / scale)));
            float r3 = fminf(127.f, fmaxf(-128.f, rintf(v.w / scale)));
            pp[q] = ((uint32_t)((int)r0 & 255)) | ((uint32_t)((int)r1 & 255) << 8)
                  | ((uint32_t)((int)r2 & 255) << 16) | ((uint32_t)((int)r3 & 255) << 24);
        }
        const int ktk = k0 >> 6;
        const int c   = (k0 >> 4) & 3;
        *reinterpret_cast<uint4*>(ob + ((size_t)ktk * 4 + c) * 4096) = pk;
    }
}

// ---------------------------------------------------------------------------
// Kernel 3: int8 GEMM = round-8 champion (256x256, 8 waves 2Mx4N, A+B
// quad-buffered 128KB LDS, depth-3 staging, reg-dbuf frags, counted vmcnt)
// + **wave phase-staggering**: waves 0-3 do {reads,stage -> MFMA}, waves 4-7
// do {MFMA -> reads,stage} per segment. Each SIMD hosts one wave of each
// parity, so the LDS pipe and the MFMA pipe are fed simultaneously instead
// of alternating in barrier lockstep (round-8's 2447 cyc/K-tile = 1170 MFMA
// + 1152 LDS, near-perfectly serialized).
// ---------------------------------------------------------------------------
__global__ __launch_bounds__(512, 2) void gemm_kernel(const uint8_t* __restrict__ xqS,
                                                      const uint8_t* __restrict__ wtS,
                                                      const float* __restrict__ xs,
                                                      const float* __restrict__ wsc,
                                                      const float* __restrict__ bias,
                                                      float* __restrict__ out) {
    extern __shared__ uint8_t lds[];
    uint8_t* ldsA = lds;            // 4 bufs * 16KB
    uint8_t* ldsB = lds + 65536;    // 4 bufs * 16KB

    const int t    = threadIdx.x;
    const int lane = t & 63;
    const int wid  = t >> 6;
    const int wm   = wid >> 2, wn = wid & 3;   // wave tile: 128 rows x 64 cols
    const bool rdFirst = (wid & 4) == 0;       // SIMD wid%4 gets one of each parity

    // XCD-aware mapping (round 8: FETCH 1.08GB -> 394MB):
    const int xcd = blockIdx.x & 7;
    const int i   = blockIdx.x >> 3;           // 0..255 local on this XCD
    const int mt  = xcd * 4 + (i & 3);         // 0..31
    const int nt  = i >> 2;                    // 0..63

    const uint8_t* aBase = xqS + (size_t)mt * (NKT * 16384);
    const uint8_t* bBase = wtS + (size_t)nt * (NKT * 16384);
    const int t16  = t * 16;
    const int wofs = wid * 1024;

    const int aRd0 = (lane >> 5) * 4096 + wm * 2048 + (lane & 31) * 16;
    const int bRd0 = (lane >> 5) * 4096 + wn * 1024 + (lane & 31) * 16;

    int32x16 acc[4][2] = {};
    int32x4 af0[4], bf0[2], af1[4], bf1[2];

    // prologue: stage K-tiles 0,1,2 (tile-major vmcnt ledger)
#pragma unroll
    for (int tt = 0; tt < 3; ++tt)
#pragma unroll
        for (int L = 0; L < 2; ++L) {
            gload_lds16(aBase + tt * 16384 + L * 8192 + t16, ldsA + tt * 16384 + L * 8192 + wofs);
            gload_lds16(bBase + tt * 16384 + L * 8192 + t16, ldsB + tt * 16384 + L * 8192 + wofs);
        }
    asm volatile("s_waitcnt vmcnt(8)" ::: "memory");   // tile 0 landed
    __builtin_amdgcn_s_barrier();
    __builtin_amdgcn_sched_barrier(0);

    // fragments (tile 0, s=0) -> f0
#pragma unroll
    for (int mr = 0; mr < 4; ++mr)
        af0[mr] = *reinterpret_cast<const int32x4*>(ldsA + aRd0 + mr * 512);
#pragma unroll
    for (int nr = 0; nr < 2; ++nr)
        bf0[nr] = *reinterpret_cast<const int32x4*>(ldsB + bRd0 + nr * 512);

    for (int kt = 0; kt < NKT; ++kt) {
        const int q  = (kt & 3) * 16384;
        const int q1 = ((kt + 1) & 3) * 16384;
        const int q3 = ((kt + 3) & 3) * 16384;
        const size_t src3 = (size_t)(kt + 3) * 16384;

        // ---- segment A: reads f1(kt) + stage(kt+3)  ||  MFMA f0(kt) ----
        // even waves issue LDS work first; odd waves MFMA first.
#define SEG_A_READS                                                                   \
        {                                                                             \
            _Pragma("unroll")                                                         \
            for (int mr = 0; mr < 4; ++mr)                                            \
                af1[mr] = *reinterpret_cast<const int32x4*>(ldsA + q + 8192 + aRd0 + mr * 512); \
            _Pragma("unroll")                                                         \
            for (int nr = 0; nr < 2; ++nr)                                            \
                bf1[nr] = *reinterpret_cast<const int32x4*>(ldsB + q + 8192 + bRd0 + nr * 512); \
            if (kt < NKT - 3) {                                                       \
                _Pragma("unroll")                                                     \
                for (int L = 0; L < 2; ++L) {                                         \
                    gload_lds16(aBase + src3 + L * 8192 + t16, ldsA + q3 + L * 8192 + wofs); \
                    gload_lds16(bBase + src3 + L * 8192 + t16, ldsB + q3 + L * 8192 + wofs); \
                }                                                                     \
            }                                                                         \
        }
#define SEG_A_MFMA                                                                    \
        {                                                                             \
            __builtin_amdgcn_s_setprio(1);                                            \
            _Pragma("unroll")                                                         \
            for (int mr = 0; mr < 4; ++mr)                                            \
                _Pragma("unroll")                                                     \
                for (int nr = 0; nr < 2; ++nr)                                        \
                    acc[mr][nr] = __builtin_amdgcn_mfma_i32_32x32x32_i8(af0[mr], bf0[nr], acc[mr][nr], 0, 0, 0); \
            __builtin_amdgcn_s_setprio(0);                                            \
        }
        if (rdFirst) {
            SEG_A_READS
            __builtin_amdgcn_sched_barrier(0);
            SEG_A_MFMA
        } else {
            SEG_A_MFMA
            __builtin_amdgcn_sched_barrier(0);
            SEG_A_READS
        }

        if (kt < NKT - 1) {
            // drain my ds_reads (WAR across barrier) + counted vmcnt
            asm volatile("s_waitcnt lgkmcnt(0)" ::: "memory");
            if (kt < NKT - 3)       asm volatile("s_waitcnt vmcnt(8)" ::: "memory");
            else if (kt == NKT - 3) asm volatile("s_waitcnt vmcnt(4)" ::: "memory");
            else                    asm volatile("s_waitcnt vmcnt(0)" ::: "memory");
            __builtin_amdgcn_s_barrier();
            __builtin_amdgcn_sched_barrier(0);

            // ---- segment B: reads f0(kt+1)  ||  MFMA f1(kt) ----
#define SEG_B_READS                                                                   \
            {                                                                         \
                _Pragma("unroll")                                                     \
                for (int mr = 0; mr < 4; ++mr)                                        \
                    af0[mr] = *reinterpret_cast<const int32x4*>(ldsA + q1 + aRd0 + mr * 512); \
                _Pragma("unroll")                                                     \
                for (int nr = 0; nr < 2; ++nr)                                        \
                    bf0[nr] = *reinterpret_cast<const int32x4*>(ldsB + q1 + bRd0 + nr * 512); \
            }
#define SEG_B_MFMA                                                                    \
            {                                                                         \
                __builtin_amdgcn_s_setprio(1);                                        \
                _Pragma("unroll")                                                     \
                for (int mr = 0; mr < 4; ++mr)                                        \
                    _Pragma("unroll")                                                 \
                    for (int nr = 0; nr < 2; ++nr)                                    \
                        acc[mr][nr] = __builtin_amdgcn_mfma_i32_32x32x32_i8(af1[mr], bf1[nr], acc[mr][nr], 0, 0, 0); \
                __builtin_amdgcn_s_setprio(0);                                        \
            }
            if (rdFirst) {
                SEG_B_READS
                __builtin_amdgcn_sched_barrier(0);
                SEG_B_MFMA
            } else {
                SEG_B_MFMA
                __builtin_amdgcn_sched_barrier(0);
                SEG_B_READS
            }
        } else {
            // last tile: just finish f1
            __builtin_amdgcn_s_setprio(1);
#pragma unroll
            for (int mr = 0; mr < 4; ++mr)
#pragma unroll
                for (int nr = 0; nr < 2; ++nr)
                    acc[mr][nr] = __builtin_amdgcn_mfma_i32_32x32x32_i8(af1[mr], bf1[nr], acc[mr][nr], 0, 0, 0);
            __builtin_amdgcn_s_setprio(0);
        }
    }

    // epilogue: C/D 32x32 layout: col = lane&31, row = (g&3)+8*(g>>2)+4*(lane>>5)
    const int row0 = mt * 256 + wm * 128;
    const int col0 = nt * 256 + wn * 64;
#pragma unroll
    for (int mr = 0; mr < 4; ++mr) {
        const int rbase = row0 + mr * 32 + 4 * (lane >> 5);
        float xsv[16];
#pragma unroll
        for (int g = 0; g < 16; ++g)
            xsv[g] = xs[rbase + (g & 3) + 8 * (g >> 2)];
#pragma unroll
        for (int nr = 0; nr < 2; ++nr) {
            const int n = col0 + nr * 32 + (lane & 31);
            const float ws_n = wsc[n];
            const float b_n  = bias[n];
#pragma unroll
            for (int g = 0; g < 16; ++g) {
                const int m = rbase + (g & 3) + 8 * (g >> 2);
                out[(size_t)m * OUT_F + n] = (float)acc[mr][nr][g] * xsv[g] * ws_n + b_n;
            }
        }
    }
}

// ---------------------------------------------------------------------------
extern "C" void kernel_launch(void* const* d_in, const int* in_sizes, int n_in,
                              void* d_out, int out_size, void* d_ws, size_t ws_size,
                              hipStream_t stream) {
    const float* x    = (const float*)d_in[0];
    const int*   wq   = (const int*)d_in[1];     // int8 pushed as int32 [4096][16384]
    const float* wsc  = (const float*)d_in[2];
    const float* bias = (const float*)d_in[3];
    float* out = (float*)d_out;

    uint8_t* ws  = (uint8_t*)d_ws;
    uint8_t* wtS = ws;                                               // 64 MiB
    uint8_t* xqS = ws + (size_t)IN_F * OUT_F;                        // 32 MiB
    float*   xs  = (float*)(ws + (size_t)IN_F * OUT_F + (size_t)NROWS * IN_F);

    (void)hipFuncSetAttribute((const void*)gemm_kernel,
                              hipFuncAttributeMaxDynamicSharedMemorySize, 131072);

    transpose_kernel<<<dim3(OUT_F / 64, IN_F / 64), 256, 0, stream>>>(wq, wtS);
    quant_kernel<<<NROWS / 8, 256, 0, stream>>>(x, xqS, xs);
    gemm_kernel<<<(NROWS / 256) * (OUT_F / 256), 512, 131072, stream>>>(xqS, wtS, xs, wsc, bias, out);
}

// Round 14
// 708.955 us; speedup vs baseline: 1.1632x; 1.0871x over previous
//
#include <hip/hip_runtime.h>
#include <cstdint>
#include <cstddef>

#define IN_F  4096
#define OUT_F 16384
#define NROWS 8192   // 2*4096 tokens
#define NKT   64     // K-tiles of 64 bytes

typedef __attribute__((ext_vector_type(4)))  int int32x4;
typedef __attribute__((ext_vector_type(16))) int int32x16;

// async global->LDS, 16B/lane (dest = wave-uniform base, HW adds lane*16)
__device__ __forceinline__ void gload_lds16(const void* g, void* s) {
    __builtin_amdgcn_global_load_lds((const __attribute__((address_space(1))) void*)g,
                                     (__attribute__((address_space(3))) void*)s,
                                     16, 0, 0);
}

// ---------------------------------------------------------------------------
// Layouts (fragment-major, shared by producers and GEMM staging):
//   xqS: [mtile 32][kt 64][c 4][row 256][16B]   c = ksub*2+kh
//   wtS: [ntile 64][kt 64][c 4][col 256][16B]
// ---------------------------------------------------------------------------

// Kernel 1: weight [K=4096][N=16384] int32 -> wtS (narrow + transpose + tile)
__global__ __launch_bounds__(256) void transpose_kernel(const int* __restrict__ w,
                                                        uint8_t* __restrict__ wtS) {
    __shared__ uint8_t tile[64][68];
    const int t  = threadIdx.x;
    const int nb = blockIdx.x * 64;
    const int kt = blockIdx.y;          // K-tile = 64 k-rows
    const int kb = kt * 64;

#pragma unroll
    for (int p = 0; p < 4; ++p) {
        const int r = p * 16 + (t >> 4);
        const int c4 = t & 15;
        int4 u = *reinterpret_cast<const int4*>(w + (size_t)(kb + r) * OUT_F + nb + c4 * 4);
        uint32_t packed = (uint32_t)(u.x & 255) | ((uint32_t)(u.y & 255) << 8)
                        | ((uint32_t)(u.z & 255) << 16) | ((uint32_t)(u.w & 255) << 24);
        *reinterpret_cast<uint32_t*>(&tile[r][c4 * 4]) = packed;
    }
    __syncthreads();

    const int col = t >> 2;             // 0..63
    const int c   = t & 3;              // ksub*2+kh
    uint4 o;
    uint32_t* op = reinterpret_cast<uint32_t*>(&o);
#pragma unroll
    for (int j = 0; j < 4; ++j) {
        const int kk = c * 16 + j * 4;
        op[j] = (uint32_t)tile[kk][col] | ((uint32_t)tile[kk + 1][col] << 8)
              | ((uint32_t)tile[kk + 2][col] << 16) | ((uint32_t)tile[kk + 3][col] << 24);
    }
    const int ntile = nb >> 8;
    const int colg  = (nb & 255) + col;
    *reinterpret_cast<uint4*>(wtS + (((size_t)ntile * NKT + kt) * 4 + c) * 4096 + colg * 16) = o;
}

// Kernel 2: per-row dynamic quant -> xqS (fragment-major) + xs
__global__ __launch_bounds__(256) void quant_kernel(const float* __restrict__ x,
                                                    uint8_t* __restrict__ xqS,
                                                    float* __restrict__ xs) {
    const int t = threadIdx.x;
    const int w = t >> 6, l = t & 63;
    const int half = l >> 5, lh = l & 31;
    const int m = blockIdx.x * 8 + w * 2 + half;
    const float* xr = x + (size_t)m * IN_F;

    float am = 0.0f;
#pragma unroll 8
    for (int jj = 0; jj < 32; ++jj) {
        float4 v = reinterpret_cast<const float4*>(xr)[jj * 32 + lh];
        am = fmaxf(am, fmaxf(fmaxf(fabsf(v.x), fabsf(v.y)),
                             fmaxf(fabsf(v.z), fabsf(v.w))));
    }
#pragma unroll
    for (int off = 16; off; off >>= 1) am = fmaxf(am, __shfl_xor(am, off));

    const float scale = fmaxf(am / 127.0f, 1e-12f);
    if (lh == 0) xs[m] = scale;

    const int mtile = m >> 8, mrow = m & 255;
    uint8_t* ob = xqS + (size_t)mtile * (NKT * 16384) + (size_t)mrow * 16;
#pragma unroll
    for (int j = 0; j < 8; ++j) {
        const int k0 = lh * 128 + j * 16;
        const float4* vp = reinterpret_cast<const float4*>(xr + k0);
        uint4 pk;
        uint32_t* pp = reinterpret_cast<uint32_t*>(&pk);
#pragma unroll
        for (int q = 0; q < 4; ++q) {
            float4 v = vp[q];
            float r0 = fminf(127.f, fmaxf(-128.f, rintf(v.x / scale)));
            float r1 = fminf(127.f, fmaxf(-128.f, rintf(v.y / scale)));
            float r2 = fminf(127.f, fmaxf(-128.f, rintf(v.z / scale)));
            float r3 = fminf(127.f, fmaxf(-128.f, rintf(v.w / scale)));
            pp[q] = ((uint32_t)((int)r0 & 255)) | ((uint32_t)((int)r1 & 255) << 8)
                  | ((uint32_t)((int)r2 & 255) << 16) | ((uint32_t)((int)r3 & 255) << 24);
        }
        const int ktk = k0 >> 6;
        const int c   = (k0 >> 4) & 3;
        *reinterpret_cast<uint4*>(ob + ((size_t)ktk * 4 + c) * 4096) = pk;
    }
}

// ---------------------------------------------------------------------------
// Kernel 3: int8 GEMM, round-8 base (256x256, 8 waves 2Mx4N, A+B quad-
// buffered 128KB LDS, depth-3 staging, counted vmcnt) with the m201 phase
// discipline: per phase {reads (+stage) -> s_barrier -> lgkmcnt(0) ->
// setprio MFMA -> s_barrier}. Overlap comes from CROSS-WAVE SKEW at the
// lgkmcnt: waves enter the MFMA cluster staggered as the LDS pipe serves
// their read batch, so early waves' MFMA hides late waves' reads.
// ---------------------------------------------------------------------------
__global__ __launch_bounds__(512, 2) void gemm_kernel(const uint8_t* __restrict__ xqS,
                                                      const uint8_t* __restrict__ wtS,
                                                      const float* __restrict__ xs,
                                                      const float* __restrict__ wsc,
                                                      const float* __restrict__ bias,
                                                      float* __restrict__ out) {
    extern __shared__ uint8_t lds[];
    uint8_t* ldsA = lds;            // 4 bufs * 16KB
    uint8_t* ldsB = lds + 65536;    // 4 bufs * 16KB

    const int t    = threadIdx.x;
    const int lane = t & 63;
    const int wid  = t >> 6;
    const int wm   = wid >> 2, wn = wid & 3;   // wave tile: 128 rows x 64 cols

    // XCD-aware mapping (round 8: FETCH 1.08GB -> 394MB):
    const int xcd = blockIdx.x & 7;
    const int i   = blockIdx.x >> 3;           // 0..255 local on this XCD
    const int mt  = xcd * 4 + (i & 3);         // 0..31
    const int nt  = i >> 2;                    // 0..63

    const uint8_t* aBase = xqS + (size_t)mt * (NKT * 16384);
    const uint8_t* bBase = wtS + (size_t)nt * (NKT * 16384);
    const int t16  = t * 16;
    const int wofs = wid * 1024;

    const int aRd0 = (lane >> 5) * 4096 + wm * 2048 + (lane & 31) * 16;
    const int bRd0 = (lane >> 5) * 4096 + wn * 1024 + (lane & 31) * 16;

    int32x16 acc[4][2] = {};
    int32x4 af[4], bf[2];

    // prologue: stage K-tiles 0,1,2 (tile-major vmcnt ledger: 12 loads)
#pragma unroll
    for (int tt = 0; tt < 3; ++tt)
#pragma unroll
        for (int L = 0; L < 2; ++L) {
            gload_lds16(aBase + tt * 16384 + L * 8192 + t16, ldsA + tt * 16384 + L * 8192 + wofs);
            gload_lds16(bBase + tt * 16384 + L * 8192 + t16, ldsB + tt * 16384 + L * 8192 + wofs);
        }
    asm volatile("s_waitcnt vmcnt(8)" ::: "memory");   // tile 0 landed (mine)
    __builtin_amdgcn_s_barrier();                      // everyone's tile 0 visible
    __builtin_amdgcn_sched_barrier(0);

    for (int kt = 0; kt < NKT; ++kt) {
        const int q  = (kt & 3) * 16384;
        const int q3 = ((kt + 3) & 3) * 16384;

        // ================= phase 0 (ksub 0) =================
        // reads for THIS phase's MFMA
#pragma unroll
        for (int mr = 0; mr < 4; ++mr)
            af[mr] = *reinterpret_cast<const int32x4*>(ldsA + q + aRd0 + mr * 512);
#pragma unroll
        for (int nr = 0; nr < 2; ++nr)
            bf[nr] = *reinterpret_cast<const int32x4*>(ldsB + q + bRd0 + nr * 512);
        // stage tile kt+3 (WAR: buf[(kt-1)&3] readers drained last iteration)
        if (kt < NKT - 3) {
            const size_t src3 = (size_t)(kt + 3) * 16384;
#pragma unroll
            for (int L = 0; L < 2; ++L) {
                gload_lds16(aBase + src3 + L * 8192 + t16, ldsA + q3 + L * 8192 + wofs);
                gload_lds16(bBase + src3 + L * 8192 + t16, ldsB + q3 + L * 8192 + wofs);
            }
        }
        __builtin_amdgcn_s_barrier();
        asm volatile("s_waitcnt lgkmcnt(0)" ::: "memory");
        __builtin_amdgcn_sched_barrier(0);
        __builtin_amdgcn_s_setprio(1);
#pragma unroll
        for (int mr = 0; mr < 4; ++mr)
#pragma unroll
            for (int nr = 0; nr < 2; ++nr)
                acc[mr][nr] = __builtin_amdgcn_mfma_i32_32x32x32_i8(af[mr], bf[nr], acc[mr][nr], 0, 0, 0);
        __builtin_amdgcn_s_setprio(0);
        __builtin_amdgcn_s_barrier();

        // ================= phase 1 (ksub 1) =================
#pragma unroll
        for (int mr = 0; mr < 4; ++mr)
            af[mr] = *reinterpret_cast<const int32x4*>(ldsA + q + 8192 + aRd0 + mr * 512);
#pragma unroll
        for (int nr = 0; nr < 2; ++nr)
            bf[nr] = *reinterpret_cast<const int32x4*>(ldsB + q + 8192 + bRd0 + nr * 512);
        __builtin_amdgcn_s_barrier();
        asm volatile("s_waitcnt lgkmcnt(0)" ::: "memory");
        __builtin_amdgcn_sched_barrier(0);
        __builtin_amdgcn_s_setprio(1);
#pragma unroll
        for (int mr = 0; mr < 4; ++mr)
#pragma unroll
            for (int nr = 0; nr < 2; ++nr)
                acc[mr][nr] = __builtin_amdgcn_mfma_i32_32x32x32_i8(af[mr], bf[nr], acc[mr][nr], 0, 0, 0);
        __builtin_amdgcn_s_setprio(0);
        // tile boundary: my tile-kt+1 stages landed (counted, never 0 mid-loop);
        // barrier makes them visible to all waves before next phase-0 reads.
        if (kt < NKT - 1) {
            if (kt < NKT - 3)       asm volatile("s_waitcnt vmcnt(8)" ::: "memory");
            else if (kt == NKT - 3) asm volatile("s_waitcnt vmcnt(4)" ::: "memory");
            else                    asm volatile("s_waitcnt vmcnt(0)" ::: "memory");
            __builtin_amdgcn_s_barrier();
            __builtin_amdgcn_sched_barrier(0);
        }
    }

    // epilogue: C/D 32x32 layout: col = lane&31, row = (g&3)+8*(g>>2)+4*(lane>>5)
    const int row0 = mt * 256 + wm * 128;
    const int col0 = nt * 256 + wn * 64;
#pragma unroll
    for (int mr = 0; mr < 4; ++mr) {
        const int rbase = row0 + mr * 32 + 4 * (lane >> 5);
        float xsv[16];
#pragma unroll
        for (int g = 0; g < 16; ++g)
            xsv[g] = xs[rbase + (g & 3) + 8 * (g >> 2)];
#pragma unroll
        for (int nr = 0; nr < 2; ++nr) {
            const int n = col0 + nr * 32 + (lane & 31);
            const float ws_n = wsc[n];
            const float b_n  = bias[n];
#pragma unroll
            for (int g = 0; g < 16; ++g) {
                const int m = rbase + (g & 3) + 8 * (g >> 2);
                out[(size_t)m * OUT_F + n] = (float)acc[mr][nr][g] * xsv[g] * ws_n + b_n;
            }
        }
    }
}

// ---------------------------------------------------------------------------
extern "C" void kernel_launch(void* const* d_in, const int* in_sizes, int n_in,
                              void* d_out, int out_size, void* d_ws, size_t ws_size,
                              hipStream_t stream) {
    const float* x    = (const float*)d_in[0];
    const int*   wq   = (const int*)d_in[1];     // int8 pushed as int32 [4096][16384]
    const float* wsc  = (const float*)d_in[2];
    const float* bias = (const float*)d_in[3];
    float* out = (float*)d_out;

    uint8_t* ws  = (uint8_t*)d_ws;
    uint8_t* wtS = ws;                                               // 64 MiB
    uint8_t* xqS = ws + (size_t)IN_F * OUT_F;                        // 32 MiB
    float*   xs  = (float*)(ws + (size_t)IN_F * OUT_F + (size_t)NROWS * IN_F);

    (void)hipFuncSetAttribute((const void*)gemm_kernel,
                              hipFuncAttributeMaxDynamicSharedMemorySize, 131072);

    transpose_kernel<<<dim3(OUT_F / 64, IN_F / 64), 256, 0, stream>>>(wq, wtS);
    quant_kernel<<<NROWS / 8, 256, 0, stream>>>(x, xqS, xs);
    gemm_kernel<<<(NROWS / 256) * (OUT_F / 256), 512, 131072, stream>>>(xqS, wtS, xs, wsc, bias, out);
}

// Round 15
// 675.371 us; speedup vs baseline: 1.2210x; 1.0497x over previous
//
#include <hip/hip_runtime.h>
#include <cstdint>
#include <cstddef>

#define IN_F  4096
#define OUT_F 16384
#define NROWS 8192   // 2*4096 tokens
#define NKT   64     // K-tiles of 64 bytes

#define NTBLK 16384  // transpose blocks (256 n-tiles x 64 k-tiles)
#define NQBLK 1024   // quant blocks (8 rows each)

typedef __attribute__((ext_vector_type(4)))  int int32x4;
typedef __attribute__((ext_vector_type(16))) int int32x16;

// async global->LDS, 16B/lane (dest = wave-uniform base, HW adds lane*16)
__device__ __forceinline__ void gload_lds16(const void* g, void* s) {
    __builtin_amdgcn_global_load_lds((const __attribute__((address_space(1))) void*)g,
                                     (__attribute__((address_space(3))) void*)s,
                                     16, 0, 0);
}

// ---------------------------------------------------------------------------
// Layouts (fragment-major, shared by producers and GEMM staging):
//   xqS: [mtile 32][kt 64][c 4][row 256][16B]   c = ksub*2+kh
//   wtS: [ntile 64][kt 64][c 4][col 256][16B]
// ---------------------------------------------------------------------------

// Fused prologue: blocks [0, NTBLK) transpose W; blocks [NTBLK, NTBLK+NQBLK)
// quantize x. Whole blocks take one branch (no divergence); independent
// inputs overlap on the device instead of serializing across two launches.
__global__ __launch_bounds__(256) void prep_kernel(const int* __restrict__ w,
                                                   const float* __restrict__ x,
                                                   uint8_t* __restrict__ wtS,
                                                   uint8_t* __restrict__ xqS,
                                                   float* __restrict__ xs) {
    __shared__ uint32_t tl[64][17];   // pad 17: write banks 2-way max (free)
    const int b = blockIdx.x;
    const int t = threadIdx.x;

    if (b < NTBLK) {
        // ---- transpose: 64n x 64k tile, register 4x4 byte-transpose ----
        const int nb = (b & 255) * 64;
        const int kt = b >> 8;          // K-tile index 0..63
        const int r  = t >> 4;          // k-quad 0..15
        const int c  = t & 15;          // n-quad 0..15

        const int* src = w + (size_t)(kt * 64 + 4 * r) * OUT_F + nb + 4 * c;
        uint32_t wk[4];
#pragma unroll
        for (int i = 0; i < 4; ++i) {
            int4 u = *reinterpret_cast<const int4*>(src + (size_t)i * OUT_F);
            wk[i] = (uint32_t)(u.x & 255) | ((uint32_t)(u.y & 255) << 8)
                  | ((uint32_t)(u.z & 255) << 16) | ((uint32_t)u.w << 24);
        }
        // byte j of wk[i] = W[kb+4r+i][nb+4c+j] -> word for n=4c+j holds k-bytes 4r..4r+3
#pragma unroll
        for (int j = 0; j < 4; ++j) {
            uint32_t v = ((wk[0] >> (8 * j)) & 255)
                       | (((wk[1] >> (8 * j)) & 255) << 8)
                       | (((wk[2] >> (8 * j)) & 255) << 16)
                       | (((wk[3] >> (8 * j)) & 255) << 24);
            tl[4 * c + j][r] = v;
        }
        __syncthreads();

        const int n  = t >> 2;          // output n-row 0..63
        const int qq = t & 3;           // 16B k-chunk 0..3
        uint4 o;
        o.x = tl[n][4 * qq];
        o.y = tl[n][4 * qq + 1];
        o.z = tl[n][4 * qq + 2];
        o.w = tl[n][4 * qq + 3];
        const int ntile = nb >> 8;
        const int colg  = (nb & 255) + n;
        *reinterpret_cast<uint4*>(wtS + (((size_t)ntile * NKT + kt) * 4 + qq) * 4096 + colg * 16) = o;
    } else {
        // ---- quant: 8 rows/block; wave w: rows 2w / 2w+1 per 32-lane half ----
        const int qb = b - NTBLK;
        const int wv = t >> 6, l = t & 63;
        const int half = l >> 5, lh = l & 31;
        const int m = qb * 8 + wv * 2 + half;
        const float* xr = x + (size_t)m * IN_F;

        float am = 0.0f;
#pragma unroll 8
        for (int jj = 0; jj < 32; ++jj) {
            float4 v = reinterpret_cast<const float4*>(xr)[jj * 32 + lh];
            am = fmaxf(am, fmaxf(fmaxf(fabsf(v.x), fabsf(v.y)),
                                 fmaxf(fabsf(v.z), fabsf(v.w))));
        }
#pragma unroll
        for (int off = 16; off; off >>= 1) am = fmaxf(am, __shfl_xor(am, off));

        const float scale = fmaxf(am / 127.0f, 1e-12f);
        if (lh == 0) xs[m] = scale;

        const int mtile = m >> 8, mrow = m & 255;
        uint8_t* ob = xqS + (size_t)mtile * (NKT * 16384) + (size_t)mrow * 16;
#pragma unroll
        for (int j = 0; j < 8; ++j) {
            const int k0 = lh * 128 + j * 16;
            const float4* vp = reinterpret_cast<const float4*>(xr + k0);
            uint4 pk;
            uint32_t* pp = reinterpret_cast<uint32_t*>(&pk);
#pragma unroll
            for (int q = 0; q < 4; ++q) {
                float4 v = vp[q];
                float r0 = fminf(127.f, fmaxf(-128.f, rintf(v.x / scale)));
                float r1 = fminf(127.f, fmaxf(-128.f, rintf(v.y / scale)));
                float r2 = fminf(127.f, fmaxf(-128.f, rintf(v.z / scale)));
                float r3 = fminf(127.f, fmaxf(-128.f, rintf(v.w / scale)));
                pp[q] = ((uint32_t)((int)r0 & 255)) | ((uint32_t)((int)r1 & 255) << 8)
                      | ((uint32_t)((int)r2 & 255) << 16) | ((uint32_t)((int)r3 & 255) << 24);
            }
            const int ktk = k0 >> 6;
            const int c   = (k0 >> 4) & 3;
            *reinterpret_cast<uint4*>(ob + ((size_t)ktk * 4 + c) * 4096) = pk;
        }
    }
}

// ---------------------------------------------------------------------------
// Kernel 3: int8 GEMM — ROUND-8 CHAMPION, unchanged (8 schedule variants all
// regressed vs this). 256x256 tile, 8 waves (2Mx4N), A+B quad-buffered LDS
// (128KB dynamic), depth-3 staging, reg-double-buffered fragments, counted
// vmcnt(8), nt-outer XCD mapping (FETCH 1.08GB -> 394MB).
// ---------------------------------------------------------------------------
__global__ __launch_bounds__(512, 2) void gemm_kernel(const uint8_t* __restrict__ xqS,
                                                      const uint8_t* __restrict__ wtS,
                                                      const float* __restrict__ xs,
                                                      const float* __restrict__ wsc,
                                                      const float* __restrict__ bias,
                                                      float* __restrict__ out) {
    extern __shared__ uint8_t lds[];
    uint8_t* ldsA = lds;            // 4 bufs * 16KB
    uint8_t* ldsB = lds + 65536;    // 4 bufs * 16KB

    const int t    = threadIdx.x;
    const int lane = t & 63;
    const int wid  = t >> 6;
    const int wm   = wid >> 2, wn = wid & 3;   // wave tile: 128 rows x 64 cols

    // XCD-aware mapping: XCD x owns mt rows 4x..4x+3; nt-outer so 4 concurrent
    // neighbors share each 1MB B panel in L2.
    const int xcd = blockIdx.x & 7;
    const int i   = blockIdx.x >> 3;           // 0..255 local on this XCD
    const int mt  = xcd * 4 + (i & 3);         // 0..31
    const int nt  = i >> 2;                    // 0..63

    const uint8_t* aBase = xqS + (size_t)mt * (NKT * 16384);
    const uint8_t* bBase = wtS + (size_t)nt * (NKT * 16384);
    const int t16  = t * 16;
    const int wofs = wid * 1024;

    const int aRd0 = (lane >> 5) * 4096 + wm * 2048 + (lane & 31) * 16;
    const int bRd0 = (lane >> 5) * 4096 + wn * 1024 + (lane & 31) * 16;

    int32x16 acc[4][2] = {};
    int32x4 af0[4], bf0[2], af1[4], bf1[2];

    // prologue: stage K-tiles 0,1,2 (tile-major vmcnt ledger)
#pragma unroll
    for (int tt = 0; tt < 3; ++tt)
#pragma unroll
        for (int L = 0; L < 2; ++L) {
            gload_lds16(aBase + tt * 16384 + L * 8192 + t16, ldsA + tt * 16384 + L * 8192 + wofs);
            gload_lds16(bBase + tt * 16384 + L * 8192 + t16, ldsB + tt * 16384 + L * 8192 + wofs);
        }
    asm volatile("s_waitcnt vmcnt(8)" ::: "memory");   // tile 0 landed
    __builtin_amdgcn_s_barrier();
    __builtin_amdgcn_sched_barrier(0);

    // fragments (tile 0, s=0) -> f0
#pragma unroll
    for (int mr = 0; mr < 4; ++mr)
        af0[mr] = *reinterpret_cast<const int32x4*>(ldsA + aRd0 + mr * 512);
#pragma unroll
    for (int nr = 0; nr < 2; ++nr)
        bf0[nr] = *reinterpret_cast<const int32x4*>(ldsB + bRd0 + nr * 512);

    for (int kt = 0; kt < NKT; ++kt) {
        const int q  = (kt & 3) * 16384;
        const int q1 = ((kt + 1) & 3) * 16384;
        const int q3 = ((kt + 3) & 3) * 16384;

        // 1. issue ds_reads (kt, s=1) -> f1 (overlap with MFMA f0 below)
#pragma unroll
        for (int mr = 0; mr < 4; ++mr)
            af1[mr] = *reinterpret_cast<const int32x4*>(ldsA + q + 8192 + aRd0 + mr * 512);
#pragma unroll
        for (int nr = 0; nr < 2; ++nr)
            bf1[nr] = *reinterpret_cast<const int32x4*>(ldsB + q + 8192 + bRd0 + nr * 512);

        // 2. stage tile kt+3 (buffer freed: all reads of tile kt-1 drained
        //    before last iteration's barrier via lgkmcnt(0))
        if (kt < NKT - 3) {
            const size_t src3 = (size_t)(kt + 3) * 16384;
#pragma unroll
            for (int L = 0; L < 2; ++L) {
                gload_lds16(aBase + src3 + L * 8192 + t16, ldsA + q3 + L * 8192 + wofs);
                gload_lds16(bBase + src3 + L * 8192 + t16, ldsB + q3 + L * 8192 + wofs);
            }
        }

        // 3. MFMA cluster on f0 (LDS pipe works on f1's reads meanwhile)
        __builtin_amdgcn_s_setprio(1);
#pragma unroll
        for (int mr = 0; mr < 4; ++mr)
#pragma unroll
            for (int nr = 0; nr < 2; ++nr)
                acc[mr][nr] = __builtin_amdgcn_mfma_i32_32x32x32_i8(af0[mr], bf0[nr], acc[mr][nr], 0, 0, 0);
        __builtin_amdgcn_s_setprio(0);

        if (kt < NKT - 1) {
            // 4. drain my ds_reads (WAR: next iter overwrites buf[kt-1]-class slot)
            asm volatile("s_waitcnt lgkmcnt(0)" ::: "memory");
            // 5. counted vmcnt: tile kt+1 (issued 2 iters ago) landed; never 0 mid-loop
            if (kt < NKT - 3)       asm volatile("s_waitcnt vmcnt(8)" ::: "memory");
            else if (kt == NKT - 3) asm volatile("s_waitcnt vmcnt(4)" ::: "memory");
            else                    asm volatile("s_waitcnt vmcnt(0)" ::: "memory");
            __builtin_amdgcn_s_barrier();
            __builtin_amdgcn_sched_barrier(0);   // pin reads below barrier

            // 6. issue ds_reads (kt+1, s=0) -> f0 (overlap with MFMA f1 below)
#pragma unroll
            for (int mr = 0; mr < 4; ++mr)
                af0[mr] = *reinterpret_cast<const int32x4*>(ldsA + q1 + aRd0 + mr * 512);
#pragma unroll
            for (int nr = 0; nr < 2; ++nr)
                bf0[nr] = *reinterpret_cast<const int32x4*>(ldsB + q1 + bRd0 + nr * 512);
        }

        // 7. MFMA cluster on f1
        __builtin_amdgcn_s_setprio(1);
#pragma unroll
        for (int mr = 0; mr < 4; ++mr)
#pragma unroll
            for (int nr = 0; nr < 2; ++nr)
                acc[mr][nr] = __builtin_amdgcn_mfma_i32_32x32x32_i8(af1[mr], bf1[nr], acc[mr][nr], 0, 0, 0);
        __builtin_amdgcn_s_setprio(0);
    }

    // epilogue: C/D 32x32 layout: col = lane&31, row = (g&3)+8*(g>>2)+4*(lane>>5)
    const int row0 = mt * 256 + wm * 128;
    const int col0 = nt * 256 + wn * 64;
#pragma unroll
    for (int mr = 0; mr < 4; ++mr) {
        const int rbase = row0 + mr * 32 + 4 * (lane >> 5);
        float xsv[16];
#pragma unroll
        for (int g = 0; g < 16; ++g)
            xsv[g] = xs[rbase + (g & 3) + 8 * (g >> 2)];
#pragma unroll
        for (int nr = 0; nr < 2; ++nr) {
            const int n = col0 + nr * 32 + (lane & 31);
            const float ws_n = wsc[n];
            const float b_n  = bias[n];
#pragma unroll
            for (int g = 0; g < 16; ++g) {
                const int m = rbase + (g & 3) + 8 * (g >> 2);
                out[(size_t)m * OUT_F + n] = (float)acc[mr][nr][g] * xsv[g] * ws_n + b_n;
            }
        }
    }
}

// ---------------------------------------------------------------------------
extern "C" void kernel_launch(void* const* d_in, const int* in_sizes, int n_in,
                              void* d_out, int out_size, void* d_ws, size_t ws_size,
                              hipStream_t stream) {
    const float* x    = (const float*)d_in[0];
    const int*   wq   = (const int*)d_in[1];     // int8 pushed as int32 [4096][16384]
    const float* wsc  = (const float*)d_in[2];
    const float* bias = (const float*)d_in[3];
    float* out = (float*)d_out;

    uint8_t* ws  = (uint8_t*)d_ws;
    uint8_t* wtS = ws;                                               // 64 MiB
    uint8_t* xqS = ws + (size_t)IN_F * OUT_F;                        // 32 MiB
    float*   xs  = (float*)(ws + (size_t)IN_F * OUT_F + (size_t)NROWS * IN_F);

    (void)hipFuncSetAttribute((const void*)gemm_kernel,
                              hipFuncAttributeMaxDynamicSharedMemorySize, 131072);

    prep_kernel<<<NTBLK + NQBLK, 256, 0, stream>>>(wq, x, wtS, xqS, xs);
    gemm_kernel<<<(NROWS / 256) * (OUT_F / 256), 512, 131072, stream>>>(xqS, wtS, xs, wsc, bias, out);
}